// Round 1
// baseline (84.007 us; speedup 1.0000x reference)
//
#include <hip/hip_runtime.h>

#define S_LEN 2048
#define B_DIM 32
#define H_DIM 1024
#define KSPLIT 16
#define KCHUNK (H_DIM / KSPLIT)   // 64
#define HTILE 256

// ---------------------------------------------------------------------------
// Kernel 1: v[b,h] = sum_k dec[b,k] * W[k,h]   (v = dec @ W, W is [out,in])
// Grid: (H/HTILE, KSPLIT) = (4,16) blocks x 256 threads.
// Each thread owns one h, accumulates all 32 b's over a k-chunk of 64,
// then atomicAdd into v (v zeroed via hipMemsetAsync before launch).
// dec[b*H+k] is thread-uniform -> scalar loads; W[k*H+h] coalesced.
// ---------------------------------------------------------------------------
__global__ __launch_bounds__(HTILE) void proj_vec_kernel(
    const float* __restrict__ dec, const float* __restrict__ W,
    float* __restrict__ v)
{
    const int h  = blockIdx.x * HTILE + threadIdx.x;
    const int k0 = blockIdx.y * KCHUNK;

    float acc[B_DIM];
#pragma unroll
    for (int b = 0; b < B_DIM; ++b) acc[b] = 0.0f;

    for (int kk = 0; kk < KCHUNK; ++kk) {
        const int k = k0 + kk;
        const float w = W[(size_t)k * H_DIM + h];
#pragma unroll
        for (int b = 0; b < B_DIM; ++b)
            acc[b] += dec[b * H_DIM + k] * w;   // uniform addr -> s_load
    }

#pragma unroll
    for (int b = 0; b < B_DIM; ++b)
        atomicAdd(&v[b * H_DIM + h], acc[b]);
}

// ---------------------------------------------------------------------------
// Kernel 2: e[b,s] = dot(enc[s,b,:], v[b,:])
// Grid: (S/4, B) blocks x 256 threads; each of the 4 waves in a block handles
// one s (same b). float4 loads: 64 lanes x 16B = 1 KiB per instruction.
// This is THE memory-bound kernel: streams 256 MiB of enc.
// ---------------------------------------------------------------------------
__global__ __launch_bounds__(256) void energy_kernel(
    const float* __restrict__ enc, const float* __restrict__ v,
    float* __restrict__ e)
{
    const int lane = threadIdx.x & 63;
    const int wv   = threadIdx.x >> 6;
    const int b    = blockIdx.y;
    const int s    = blockIdx.x * 4 + wv;

    const float4* __restrict__ encp =
        reinterpret_cast<const float4*>(enc + ((size_t)s * B_DIM + b) * H_DIM);
    const float4* __restrict__ vp =
        reinterpret_cast<const float4*>(v + (size_t)b * H_DIM);

    float acc = 0.0f;
#pragma unroll
    for (int i = 0; i < 4; ++i) {
        const float4 a = encp[lane + 64 * i];
        const float4 w = vp[lane + 64 * i];
        acc += a.x * w.x + a.y * w.y + a.z * w.z + a.w * w.w;
    }

#pragma unroll
    for (int off = 32; off; off >>= 1)
        acc += __shfl_xor(acc, off, 64);

    if (lane == 0) e[(size_t)b * S_LEN + s] = acc;
}

// ---------------------------------------------------------------------------
// Kernel 3: out[b,0,s] = softmax_s(e[b,s]).  One block per b (32 blocks).
// 256 threads x 8 elements each. Bias term c[b] omitted: constant per row,
// softmax-invariant.
// ---------------------------------------------------------------------------
__global__ __launch_bounds__(256) void softmax_kernel(
    const float* __restrict__ e, float* __restrict__ out)
{
    __shared__ float red[4];
    const int b    = blockIdx.x;
    const int tid  = threadIdx.x;
    const int lane = tid & 63;
    const int wv   = tid >> 6;
    const float* __restrict__ row = e + (size_t)b * S_LEN;

    float vals[8];
    float m = -1e30f;
#pragma unroll
    for (int i = 0; i < 8; ++i) {
        vals[i] = row[tid + 256 * i];
        m = fmaxf(m, vals[i]);
    }
#pragma unroll
    for (int off = 32; off; off >>= 1)
        m = fmaxf(m, __shfl_xor(m, off, 64));
    if (lane == 0) red[wv] = m;
    __syncthreads();
    m = fmaxf(fmaxf(red[0], red[1]), fmaxf(red[2], red[3]));

    float sum = 0.0f;
#pragma unroll
    for (int i = 0; i < 8; ++i) {
        vals[i] = __expf(vals[i] - m);
        sum += vals[i];
    }
#pragma unroll
    for (int off = 32; off; off >>= 1)
        sum += __shfl_xor(sum, off, 64);
    __syncthreads();                 // red reuse hazard
    if (lane == 0) red[wv] = sum;
    __syncthreads();
    sum = red[0] + red[1] + red[2] + red[3];

    const float inv = 1.0f / sum;
#pragma unroll
    for (int i = 0; i < 8; ++i)
        out[(size_t)b * S_LEN + tid + 256 * i] = vals[i] * inv;
}

// ---------------------------------------------------------------------------
extern "C" void kernel_launch(void* const* d_in, const int* in_sizes, int n_in,
                              void* d_out, int out_size, void* d_ws, size_t ws_size,
                              hipStream_t stream)
{
    const float* dec = (const float*)d_in[0];   // [B,H]
    const float* enc = (const float*)d_in[1];   // [S,B,H]
    const float* W   = (const float*)d_in[2];   // [H,H]
    // d_in[3] = bias: constant-per-row contribution, softmax-invariant -> unused
    float* out = (float*)d_out;                 // [B,1,S] flat

    float* v = (float*)d_ws;                    // B*H floats   (128 KiB)
    float* e = v + B_DIM * H_DIM;               // B*S floats   (256 KiB)

    hipMemsetAsync(v, 0, B_DIM * H_DIM * sizeof(float), stream);

    proj_vec_kernel<<<dim3(H_DIM / HTILE, KSPLIT), HTILE, 0, stream>>>(dec, W, v);
    energy_kernel<<<dim3(S_LEN / 4, B_DIM), 256, 0, stream>>>(enc, v, e);
    softmax_kernel<<<B_DIM, 256, 0, stream>>>(e, out);
}

// Round 2
// 79.052 us; speedup vs baseline: 1.0627x; 1.0627x over previous
//
#include <hip/hip_runtime.h>

#define S_LEN 2048
#define B_DIM 32
#define H_DIM 1024
#define KSPLIT 16
#define KCHUNK (H_DIM / KSPLIT)   // 64
#define HTILE 256

// ---------------------------------------------------------------------------
// Kernel 1: v[b,h] = sum_k dec[b,k] * W[k,h]   (v = dec @ W, W is [out,in])
// Grid: (H/HTILE, KSPLIT) = (4,16) blocks x 256 threads, atomicAdd into
// memset-zeroed v. dec loads thread-uniform -> s_load; W coalesced.
// ---------------------------------------------------------------------------
__global__ __launch_bounds__(HTILE) void proj_vec_kernel(
    const float* __restrict__ dec, const float* __restrict__ W,
    float* __restrict__ v)
{
    const int h  = blockIdx.x * HTILE + threadIdx.x;
    const int k0 = blockIdx.y * KCHUNK;

    float acc[B_DIM];
#pragma unroll
    for (int b = 0; b < B_DIM; ++b) acc[b] = 0.0f;

    for (int kk = 0; kk < KCHUNK; ++kk) {
        const int k = k0 + kk;
        const float w = W[(size_t)k * H_DIM + h];
#pragma unroll
        for (int b = 0; b < B_DIM; ++b)
            acc[b] += dec[b * H_DIM + k] * w;   // uniform addr -> s_load
    }

#pragma unroll
    for (int b = 0; b < B_DIM; ++b)
        atomicAdd(&v[b * H_DIM + h], acc[b]);
}

// ---------------------------------------------------------------------------
// Kernel 2: e[b,s] = dot(enc[s,b,:], v[b,:])
// Grid: (B/4, S) = (8, 2048), blockIdx.x FASTEST -> sequential HBM stream:
// block (x,y) reads enc[y, 4x:4x+4, :] = 16 KB contiguous; 8 consecutive
// blocks cover one full 128 KB s-slab. Wave wv handles b = 4x+wv.
// ---------------------------------------------------------------------------
__global__ __launch_bounds__(256) void energy_kernel(
    const float* __restrict__ enc, const float* __restrict__ v,
    float* __restrict__ e)
{
    const int lane = threadIdx.x & 63;
    const int wv   = threadIdx.x >> 6;
    const int s    = blockIdx.y;
    const int b    = blockIdx.x * 4 + wv;

    const float4* __restrict__ encp =
        reinterpret_cast<const float4*>(enc + ((size_t)s * B_DIM + b) * H_DIM);
    const float4* __restrict__ vp =
        reinterpret_cast<const float4*>(v + (size_t)b * H_DIM);

    float acc = 0.0f;
#pragma unroll
    for (int i = 0; i < 4; ++i) {
        const float4 a = encp[lane + 64 * i];
        const float4 w = vp[lane + 64 * i];
        acc += a.x * w.x + a.y * w.y + a.z * w.z + a.w * w.w;
    }

#pragma unroll
    for (int off = 32; off; off >>= 1)
        acc += __shfl_xor(acc, off, 64);

    if (lane == 0) e[(size_t)b * S_LEN + s] = acc;
}

// ---------------------------------------------------------------------------
// Kernel 3: out[b,0,s] = softmax_s(e[b,s]).  One block per b (32 blocks).
// Bias term c[b] omitted: constant per row, softmax-invariant.
// ---------------------------------------------------------------------------
__global__ __launch_bounds__(256) void softmax_kernel(
    const float* __restrict__ e, float* __restrict__ out)
{
    __shared__ float red[4];
    const int b    = blockIdx.x;
    const int tid  = threadIdx.x;
    const int lane = tid & 63;
    const int wv   = tid >> 6;
    const float* __restrict__ row = e + (size_t)b * S_LEN;

    float vals[8];
    float m = -1e30f;
#pragma unroll
    for (int i = 0; i < 8; ++i) {
        vals[i] = row[tid + 256 * i];
        m = fmaxf(m, vals[i]);
    }
#pragma unroll
    for (int off = 32; off; off >>= 1)
        m = fmaxf(m, __shfl_xor(m, off, 64));
    if (lane == 0) red[wv] = m;
    __syncthreads();
    m = fmaxf(fmaxf(red[0], red[1]), fmaxf(red[2], red[3]));

    float sum = 0.0f;
#pragma unroll
    for (int i = 0; i < 8; ++i) {
        vals[i] = __expf(vals[i] - m);
        sum += vals[i];
    }
#pragma unroll
    for (int off = 32; off; off >>= 1)
        sum += __shfl_xor(sum, off, 64);
    __syncthreads();                 // red reuse hazard
    if (lane == 0) red[wv] = sum;
    __syncthreads();
    sum = red[0] + red[1] + red[2] + red[3];

    const float inv = 1.0f / sum;
#pragma unroll
    for (int i = 0; i < 8; ++i)
        out[(size_t)b * S_LEN + tid + 256 * i] = vals[i] * inv;
}

// ---------------------------------------------------------------------------
extern "C" void kernel_launch(void* const* d_in, const int* in_sizes, int n_in,
                              void* d_out, int out_size, void* d_ws, size_t ws_size,
                              hipStream_t stream)
{
    const float* dec = (const float*)d_in[0];   // [B,H]
    const float* enc = (const float*)d_in[1];   // [S,B,H]
    const float* W   = (const float*)d_in[2];   // [H,H]
    // d_in[3] = bias: constant-per-row contribution, softmax-invariant -> unused
    float* out = (float*)d_out;                 // [B,1,S] flat

    float* v = (float*)d_ws;                    // B*H floats   (128 KiB)
    float* e = v + B_DIM * H_DIM;               // B*S floats   (256 KiB)

    hipMemsetAsync(v, 0, B_DIM * H_DIM * sizeof(float), stream);

    proj_vec_kernel<<<dim3(H_DIM / HTILE, KSPLIT), HTILE, 0, stream>>>(dec, W, v);
    energy_kernel<<<dim3(B_DIM / 4, S_LEN), 256, 0, stream>>>(enc, v, e);
    softmax_kernel<<<B_DIM, 256, 0, stream>>>(e, out);
}

// Round 3
// 71.476 us; speedup vs baseline: 1.1753x; 1.1060x over previous
//
#include <hip/hip_runtime.h>

#define S_LEN 2048
#define B_DIM 32
#define H_DIM 1024
#define ROWS 4   // s-rows per wave in energy kernel

typedef float fx4 __attribute__((ext_vector_type(4)));

// ---------------------------------------------------------------------------
// Kernel 1: v[b,h] = sum_k dec[b,k] * W[k,h]   (v = dec @ W, W is [out,in])
// Grid: (H/256, B) = (4, 32) blocks x 256 threads. Full-K per block: no
// k-split, no atomics, no memset. XCD mapping: id%8 keys on the h-tile, so
// each XCD's L2 sees ~1 MB of W; L3 dedups cross-XCD re-reads.
// dec loads are thread-uniform -> scalar loads; W loads coalesced (1 KiB/instr).
// 1024 FMAs/thread over 4 accumulators ~ 0.9 us.
// ---------------------------------------------------------------------------
__global__ __launch_bounds__(256) void proj_vec_kernel(
    const float* __restrict__ dec, const float* __restrict__ W,
    float* __restrict__ v)
{
    const int h = blockIdx.x * 256 + threadIdx.x;
    const int b = blockIdx.y;
    const float* __restrict__ drow = dec + (size_t)b * H_DIM;

    float a0 = 0.f, a1 = 0.f, a2 = 0.f, a3 = 0.f;
    for (int k = 0; k < H_DIM; k += 4) {
        a0 += drow[k + 0] * W[(size_t)(k + 0) * H_DIM + h];
        a1 += drow[k + 1] * W[(size_t)(k + 1) * H_DIM + h];
        a2 += drow[k + 2] * W[(size_t)(k + 2) * H_DIM + h];
        a3 += drow[k + 3] * W[(size_t)(k + 3) * H_DIM + h];
    }
    v[(size_t)b * H_DIM + h] = (a0 + a1) + (a2 + a3);
}

// ---------------------------------------------------------------------------
// Kernel 2: e[b,s] = dot(enc[s,b,:], v[b,:])
// Grid: (B/4, S/ROWS) = (8, 512), x fastest -> 8 consecutive blocks cover a
// full 4-row x 128 KB region sequentially. Wave wv owns b = 4x+wv and ROWS
// consecutive s. v row lives in 16 VGPRs (loaded once per wave); 16
// independent nontemporal enc loads in flight; 4 reduce chains interleaved;
// lane 0 stores one float4.
// ---------------------------------------------------------------------------
__global__ __launch_bounds__(256) void energy_kernel(
    const float* __restrict__ enc, const float* __restrict__ v,
    float* __restrict__ e)
{
    const int lane = threadIdx.x & 63;
    const int wv   = threadIdx.x >> 6;
    const int b    = blockIdx.x * 4 + wv;
    const int s0   = blockIdx.y * ROWS;

    const fx4* __restrict__ vp =
        reinterpret_cast<const fx4*>(v + (size_t)b * H_DIM);
    fx4 vf[4];
#pragma unroll
    for (int i = 0; i < 4; ++i) vf[i] = vp[lane + 64 * i];

    float acc[ROWS];
#pragma unroll
    for (int r = 0; r < ROWS; ++r) {
        const fx4* __restrict__ ep = reinterpret_cast<const fx4*>(
            enc + ((size_t)(s0 + r) * B_DIM + b) * H_DIM);
        fx4 a[4];
#pragma unroll
        for (int i = 0; i < 4; ++i)
            a[i] = __builtin_nontemporal_load(&ep[lane + 64 * i]);
        float t = 0.f;
#pragma unroll
        for (int i = 0; i < 4; ++i)
            t += a[i].x * vf[i].x + a[i].y * vf[i].y +
                 a[i].z * vf[i].z + a[i].w * vf[i].w;
        acc[r] = t;
    }

#pragma unroll
    for (int off = 32; off; off >>= 1) {
#pragma unroll
        for (int r = 0; r < ROWS; ++r)
            acc[r] += __shfl_xor(acc[r], off, 64);
    }

    if (lane == 0) {
        fx4 o;
        o.x = acc[0]; o.y = acc[1]; o.z = acc[2]; o.w = acc[3];
        *reinterpret_cast<fx4*>(e + (size_t)b * S_LEN + s0) = o;
    }
}

// ---------------------------------------------------------------------------
// Kernel 3: out[b,0,s] = softmax_s(e[b,s]).  One block per b (32 blocks).
// Bias term c[b] omitted: constant per row, softmax-invariant.
// ---------------------------------------------------------------------------
__global__ __launch_bounds__(256) void softmax_kernel(
    const float* __restrict__ e, float* __restrict__ out)
{
    __shared__ float red[4];
    const int b    = blockIdx.x;
    const int tid  = threadIdx.x;
    const int lane = tid & 63;
    const int wv   = tid >> 6;
    const float* __restrict__ row = e + (size_t)b * S_LEN;

    float vals[8];
    float m = -1e30f;
#pragma unroll
    for (int i = 0; i < 8; ++i) {
        vals[i] = row[tid + 256 * i];
        m = fmaxf(m, vals[i]);
    }
#pragma unroll
    for (int off = 32; off; off >>= 1)
        m = fmaxf(m, __shfl_xor(m, off, 64));
    if (lane == 0) red[wv] = m;
    __syncthreads();
    m = fmaxf(fmaxf(red[0], red[1]), fmaxf(red[2], red[3]));

    float sum = 0.0f;
#pragma unroll
    for (int i = 0; i < 8; ++i) {
        vals[i] = __expf(vals[i] - m);
        sum += vals[i];
    }
#pragma unroll
    for (int off = 32; off; off >>= 1)
        sum += __shfl_xor(sum, off, 64);
    __syncthreads();                 // red reuse hazard
    if (lane == 0) red[wv] = sum;
    __syncthreads();
    sum = red[0] + red[1] + red[2] + red[3];

    const float inv = 1.0f / sum;
#pragma unroll
    for (int i = 0; i < 8; ++i)
        out[(size_t)b * S_LEN + tid + 256 * i] = vals[i] * inv;
}

// ---------------------------------------------------------------------------
extern "C" void kernel_launch(void* const* d_in, const int* in_sizes, int n_in,
                              void* d_out, int out_size, void* d_ws, size_t ws_size,
                              hipStream_t stream)
{
    const float* dec = (const float*)d_in[0];   // [B,H]
    const float* enc = (const float*)d_in[1];   // [S,B,H]
    const float* W   = (const float*)d_in[2];   // [H,H]
    // d_in[3] = bias: constant-per-row contribution, softmax-invariant -> unused
    float* out = (float*)d_out;                 // [B,1,S] flat

    float* v = (float*)d_ws;                    // B*H floats   (128 KiB)
    float* e = v + B_DIM * H_DIM;               // B*S floats   (256 KiB)

    proj_vec_kernel<<<dim3(H_DIM / 256, B_DIM), 256, 0, stream>>>(dec, W, v);
    energy_kernel<<<dim3(B_DIM / 4, S_LEN / ROWS), 256, 0, stream>>>(enc, v, e);
    softmax_kernel<<<B_DIM, 256, 0, stream>>>(e, out);
}

// Round 4
// 60.402 us; speedup vs baseline: 1.3908x; 1.1833x over previous
//
#include <hip/hip_runtime.h>

#define S_LEN 2048
#define B_DIM 32
#define H_DIM 1024
#define ROWS 8       // s-rows per wave in energy kernel
#define KSPLIT 4     // k-split partials in proj
#define KCH (H_DIM / KSPLIT)  // 256

typedef float fx4 __attribute__((ext_vector_type(4)));

// ---------------------------------------------------------------------------
// Kernel 1: v4[kp,b,h] = sum_{k in chunk kp} dec[b,k] * W[k,h]
// Grid: (H/256, B, KSPLIT) = (4, 32, 4) = 512 blocks x 256 threads.
// 4x the blocks of the full-K version -> hides the cold-HBM W fetch (W is
// evicted from L3 every replay by the 256 MiB enc stream). No atomics, no
// memset: energy sums the 4 partials (L2/L3-resident) on load.
// dec loads thread-uniform -> s_load; W loads coalesced (256 B/wave/instr).
// ---------------------------------------------------------------------------
__global__ __launch_bounds__(256) void proj_vec_kernel(
    const float* __restrict__ dec, const float* __restrict__ W,
    float* __restrict__ v4)
{
    const int h  = blockIdx.x * 256 + threadIdx.x;
    const int b  = blockIdx.y;
    const int kp = blockIdx.z;
    const int k0 = kp * KCH;
    const float* __restrict__ drow = dec + (size_t)b * H_DIM;

    float a0 = 0.f, a1 = 0.f, a2 = 0.f, a3 = 0.f;
    for (int kk = 0; kk < KCH; kk += 4) {
        const int k = k0 + kk;
        a0 += drow[k + 0] * W[(size_t)(k + 0) * H_DIM + h];
        a1 += drow[k + 1] * W[(size_t)(k + 1) * H_DIM + h];
        a2 += drow[k + 2] * W[(size_t)(k + 2) * H_DIM + h];
        a3 += drow[k + 3] * W[(size_t)(k + 3) * H_DIM + h];
    }
    v4[((size_t)kp * B_DIM + b) * H_DIM + h] = (a0 + a1) + (a2 + a3);
}

// ---------------------------------------------------------------------------
// Kernel 2: e[b,s] = dot(enc[s,b,:], v[b,:]),  v = sum of 4 partials.
// Grid: (B/4, S/ROWS) = (8, 256), x fastest -> 8 consecutive blocks cover a
// full 8-row x 128 KB slab (1 MB) sequentially. Wave wv owns b = 4x+wv and
// 8 consecutive s. v row summed once into 16 VGPRs; enc read via plain
// float4 loads (m13's 6.29 TB/s recipe), 16 loads in flight per half-group,
// two half-groups to bound VGPR pressure. 8 interleaved reduce chains.
// ---------------------------------------------------------------------------
__global__ __launch_bounds__(256) void energy_kernel(
    const float* __restrict__ enc, const float* __restrict__ v4,
    float* __restrict__ e)
{
    const int lane = threadIdx.x & 63;
    const int wv   = threadIdx.x >> 6;
    const int b    = blockIdx.x * 4 + wv;
    const int s0   = blockIdx.y * ROWS;

    fx4 vf[4];
#pragma unroll
    for (int i = 0; i < 4; ++i) {
        fx4 t = {0.f, 0.f, 0.f, 0.f};
#pragma unroll
        for (int kp = 0; kp < KSPLIT; ++kp) {
            const fx4* __restrict__ p = reinterpret_cast<const fx4*>(
                v4 + ((size_t)kp * B_DIM + b) * H_DIM);
            t += p[lane + 64 * i];
        }
        vf[i] = t;
    }

    float acc[ROWS];
    for (int g = 0; g < 2; ++g) {
        fx4 a[4][4];
#pragma unroll
        for (int r = 0; r < 4; ++r) {
            const fx4* __restrict__ ep = reinterpret_cast<const fx4*>(
                enc + ((size_t)(s0 + g * 4 + r) * B_DIM + b) * H_DIM);
#pragma unroll
            for (int i = 0; i < 4; ++i)
                a[r][i] = ep[lane + 64 * i];
        }
#pragma unroll
        for (int r = 0; r < 4; ++r) {
            float t = 0.f;
#pragma unroll
            for (int i = 0; i < 4; ++i)
                t += a[r][i].x * vf[i].x + a[r][i].y * vf[i].y +
                     a[r][i].z * vf[i].z + a[r][i].w * vf[i].w;
            acc[g * 4 + r] = t;
        }
    }

#pragma unroll
    for (int off = 32; off; off >>= 1) {
#pragma unroll
        for (int r = 0; r < ROWS; ++r)
            acc[r] += __shfl_xor(acc[r], off, 64);
    }

    if (lane == 0) {
        fx4 o0, o1;
        o0.x = acc[0]; o0.y = acc[1]; o0.z = acc[2]; o0.w = acc[3];
        o1.x = acc[4]; o1.y = acc[5]; o1.z = acc[6]; o1.w = acc[7];
        fx4* ep = reinterpret_cast<fx4*>(e + (size_t)b * S_LEN + s0);
        ep[0] = o0;
        ep[1] = o1;
    }
}

// ---------------------------------------------------------------------------
// Kernel 3: out[b,0,s] = softmax_s(e[b,s]).  One block per b (32 blocks).
// Bias term c[b] omitted: constant per row, softmax-invariant.
// ---------------------------------------------------------------------------
__global__ __launch_bounds__(256) void softmax_kernel(
    const float* __restrict__ e, float* __restrict__ out)
{
    __shared__ float red[4];
    const int b    = blockIdx.x;
    const int tid  = threadIdx.x;
    const int lane = tid & 63;
    const int wv   = tid >> 6;
    const float* __restrict__ row = e + (size_t)b * S_LEN;

    float vals[8];
    float m = -1e30f;
#pragma unroll
    for (int i = 0; i < 8; ++i) {
        vals[i] = row[tid + 256 * i];
        m = fmaxf(m, vals[i]);
    }
#pragma unroll
    for (int off = 32; off; off >>= 1)
        m = fmaxf(m, __shfl_xor(m, off, 64));
    if (lane == 0) red[wv] = m;
    __syncthreads();
    m = fmaxf(fmaxf(red[0], red[1]), fmaxf(red[2], red[3]));

    float sum = 0.0f;
#pragma unroll
    for (int i = 0; i < 8; ++i) {
        vals[i] = __expf(vals[i] - m);
        sum += vals[i];
    }
#pragma unroll
    for (int off = 32; off; off >>= 1)
        sum += __shfl_xor(sum, off, 64);
    __syncthreads();                 // red reuse hazard
    if (lane == 0) red[wv] = sum;
    __syncthreads();
    sum = red[0] + red[1] + red[2] + red[3];

    const float inv = 1.0f / sum;
#pragma unroll
    for (int i = 0; i < 8; ++i)
        out[(size_t)b * S_LEN + tid + 256 * i] = vals[i] * inv;
}

// ---------------------------------------------------------------------------
extern "C" void kernel_launch(void* const* d_in, const int* in_sizes, int n_in,
                              void* d_out, int out_size, void* d_ws, size_t ws_size,
                              hipStream_t stream)
{
    const float* dec = (const float*)d_in[0];   // [B,H]
    const float* enc = (const float*)d_in[1];   // [S,B,H]
    const float* W   = (const float*)d_in[2];   // [H,H]
    // d_in[3] = bias: constant-per-row contribution, softmax-invariant -> unused
    float* out = (float*)d_out;                 // [B,1,S] flat

    float* v4 = (float*)d_ws;                   // KSPLIT*B*H floats (512 KiB)
    float* e  = v4 + KSPLIT * B_DIM * H_DIM;    // B*S floats        (256 KiB)

    proj_vec_kernel<<<dim3(H_DIM / 256, B_DIM, KSPLIT), 256, 0, stream>>>(dec, W, v4);
    energy_kernel<<<dim3(B_DIM / 4, S_LEN / ROWS), 256, 0, stream>>>(enc, v4, e);
    softmax_kernel<<<B_DIM, 256, 0, stream>>>(e, out);
}